// Round 15
// baseline (121.639 us; speedup 1.0000x reference)
//
#include <hip/hip_runtime.h>

// RNN: h_t = tanh(x_t*w_ih + b_ih + b_hh + W_hh h_{t-1});  out = h_T . w_fc + b_fc
// B=4096, T=512, I=1, H=16, O=1.
//
// Round 11: MFMA recurrence. The DPP family is exhausted (r5/r9/r10 all
// ~110 cyc/step: issue ~54 conserved across layouts + ~50 exposed chain).
// v_mfma_f32_16x16x16_f16 computes the whole 16x16 matvec for 16 batches in
// ONE issue slot. Zero-shuffle recurrence: B-frag layout (col n = lane&15,
// k = 4*(lane>>4)+j) == D layout (col n = lane&15, m = 4*(lane>>4)+j, m89-
// verified), so tanh(D) converts in-lane into next step's B. Per step:
//   4 fmaf (C = C2LE*(x*wih + b), lane-local) + 1 MFMA
//   + 4x {exp2, add, rcp, fmaf(-2,rc,1)} + 4 f16 cvt (RNE)
// ~27 issue slots for 16 batches + ~55 cyc chain -> ~60 cyc/step vs 110.
//
// Precision: B carries h (|h|<=1) in f16 via RNE scalar converts (NOT
// cvt_pkrtz/RTZ): per-step quantization <= 2.4e-4, tanh-contracted.
// A = C2LE * w_hh[m][k] in f16 (A-frag: row m = lane&15, k = 4*(lane>>4)+j).
// Grid: 4096/16 = 256 blocks x 64 threads -> 1 wave/CU, latency-bound by
// design (only 256 independent MFMA chains exist).
//
// Pre-committed fallbacks: absmax O(0.1+) => A-layout transposed (swap to
// w_hh[(4g+j)*16 + (lane&15)]); absmax 6e-3..5e-2 => residual two-MFMA.

constexpr int T_STEPS = 512;
constexpr float C2LE = 2.8853900817779268f; // 2*log2(e)

typedef _Float16 half4 __attribute__((ext_vector_type(4)));
typedef float    f32x4 __attribute__((ext_vector_type(4)));

__global__ __launch_bounds__(64) void rnn_mfma(
    const float* __restrict__ x,
    const float* __restrict__ w_ih,
    const float* __restrict__ w_hh,
    const float* __restrict__ b_ih,
    const float* __restrict__ b_hh,
    const float* __restrict__ w_fc,
    const float* __restrict__ b_fc,
    float* __restrict__ out)
{
    const int lane  = threadIdx.x;        // 0..63
    const int n     = lane & 15;          // B/D column = batch within tile
    const int g     = lane >> 4;          // lane group 0..3
    const int batch = blockIdx.x * 16 + n;

    // A fragment: A[m][k] = C2LE * w_hh[m][k], row m = lane&15, k = 4g+j.
    half4 a;
    #pragma unroll
    for (int j = 0; j < 4; ++j)
        a[j] = (_Float16)(C2LE * w_hh[(lane & 15) * 16 + 4 * g + j]);

    // Per-lane m-constants for C/D rows m = 4g+j (bias/x enter via C).
    float wihc[4], biasc[4], wfc4[4];
    #pragma unroll
    for (int j = 0; j < 4; ++j) {
        const int m = 4 * g + j;
        wihc[j]  = w_ih[m] * C2LE;
        biasc[j] = (b_ih[m] + b_hh[m]) * C2LE;
        wfc4[j]  = w_fc[m];
    }

    const float* xb = x + (size_t)batch * T_STEPS;  // x[batch,:,0], 16B aligned

    half4 bfrag;                     // h in f16 (B operand)
    f32x4 hf;                        // h in f32 (epilogue precision)
    #pragma unroll
    for (int j = 0; j < 4; ++j) { bfrag[j] = (_Float16)0.0f; hf[j] = 0.0f; }

    // One timestep: C-prep (indep of h) -> MFMA -> per-lane tanh -> f16 cvt.
    #define STEP(xval) {                                                       \
        f32x4 c;                                                               \
        _Pragma("unroll")                                                      \
        for (int j = 0; j < 4; ++j) c[j] = fmaf((xval), wihc[j], biasc[j]);    \
        const f32x4 d = __builtin_amdgcn_mfma_f32_16x16x16f16(a, bfrag, c,     \
                                                              0, 0, 0);        \
        _Pragma("unroll")                                                      \
        for (int j = 0; j < 4; ++j) {                                          \
            const float e_ = __builtin_amdgcn_exp2f(d[j]);                     \
            const float rc = __builtin_amdgcn_rcpf(e_ + 1.0f);                 \
            hf[j] = fmaf(-2.0f, rc, 1.0f);                                     \
            bfrag[j] = (_Float16)hf[j];        /* RNE convert */               \
        }                                                                      \
    }

    // 4 steps/iter; next x quad prefetched (per-lane row, L1/L2-resident).
    float4 xcur = *reinterpret_cast<const float4*>(xb);
    #pragma unroll 1
    for (int t = 0; t < T_STEPS; t += 4) {
        const int nxt = (t + 4 < T_STEPS) ? (t + 4) : 0;   // last iter: dummy
        const float4 xn = *reinterpret_cast<const float4*>(xb + nxt);
        STEP(xcur.x) STEP(xcur.y) STEP(xcur.z) STEP(xcur.w)
        xcur = xn;
    }
    #undef STEP

    // out[batch] = dot(h, w_fc) + b_fc. Lane (n,g) holds h[m=4g+j]; partial
    // dot in-lane, then sum the 4 g-groups (lanes n, n+16, n+32, n+48).
    float v = 0.0f;
    #pragma unroll
    for (int j = 0; j < 4; ++j) v = fmaf(hf[j], wfc4[j], v);
    v += __shfl_xor(v, 16);
    v += __shfl_xor(v, 32);
    if (g == 0) out[batch] = v + b_fc[0];
}

extern "C" void kernel_launch(void* const* d_in, const int* in_sizes, int n_in,
                              void* d_out, int out_size, void* d_ws, size_t ws_size,
                              hipStream_t stream) {
    const float* x    = (const float*)d_in[0];
    const float* w_ih = (const float*)d_in[1];
    const float* w_hh = (const float*)d_in[2];
    const float* b_ih = (const float*)d_in[3];
    const float* b_hh = (const float*)d_in[4];
    const float* w_fc = (const float*)d_in[5];
    const float* b_fc = (const float*)d_in[6];
    float* out = (float*)d_out;

    const int B = out_size;                 // 4096
    const int blocks = B / 16;              // 256 blocks x 1 wave -> 1/CU
    rnn_mfma<<<blocks, 64, 0, stream>>>(x, w_ih, w_hh, b_ih, b_hh, w_fc, b_fc, out);
}